// Round 10
// baseline (101.110 us; speedup 1.0000x reference)
//
#include <hip/hip_runtime.h>
#include <stdint.h>

#define HIDDEN 4096
#define RANK 64
#define ROWLEN (HIDDEN + RANK)   // 4160

// ============================================================================
// Hypothesis ledger (all kernels integer-exact emulations; error always 1.0):
//  R3: scale f16(RN32(m/7)),  RN32 div, half-even   -> FAILED
//  R4: scale f16(true m/7),   f64 div,  half-even   -> FAILED
//  R5/R6: no-f16 scales,      exact div, half-even  -> FAILED
//  R7/R8: tie rules away/up,  RN32 div              -> FAILED
//  R9: XLA-rcp quantize, scale f16(RN32(m/7))       -> FAILED
//  Mechanical np recompute == R3/R4 -> golden is NOT numpy. "ref=np" = the
//  npz-loaded jax EXPECTED => golden = XLA-CPU compiled arithmetic.
//  R10 (this): XLA constant-divisor rewrite applies to the SCALE only:
//      scale = f16_RNE( RN32( m * RN32(1/7) ) )   [absmax/Q_MAX, const div]
//      q     = clip( rne( RN32( core / scale ) ), +-7 )  [data-dep div: true]
//  Scale-side f16-boundary straddles (~few rows) flip dozens of elements by
//  exactly +-1 -> absmax 1.0, invariant across R1-R9's quantize-side edits.
// ============================================================================

// IEEE RN32 division a/b for positive normal a,b via integer math (immune to
// compiler FP modes). Audited: 1.0/7.0 -> 0x3E124925.
__device__ __forceinline__ uint32_t softdiv_rn32_bits(uint32_t abits, uint32_t bbits) {
    uint32_t Ma = (abits & 0x7FFFFFu) | 0x800000u;
    uint32_t Mb = (bbits & 0x7FFFFFu) | 0x800000u;
    int Ea = (int)((abits >> 23) & 0xFFu);
    int Eb = (int)((bbits >> 23) & 0xFFu);
    uint64_t num = ((uint64_t)Ma) << 25;
    uint64_t qi  = num / (uint64_t)Mb;
    uint64_t rem = num - qi * (uint64_t)Mb;
    int sh = (uint32_t)(qi >> 25) ? 2 : 1;
    uint32_t M  = (uint32_t)(qi >> sh);
    uint32_t rb = ((uint32_t)(qi >> (sh - 1))) & 1u;
    uint32_t st = ((((uint32_t)qi) & (uint32_t)(sh - 1)) != 0u) | (rem != 0ull);
    if (rb && (st || (M & 1u))) M++;
    int E = sh + Ea - Eb - 25;
    if (M == (1u << 24)) { M >>= 1; E += 1; }
    return ((uint32_t)(E + 150) << 23) | (M & 0x7FFFFFu);
}

// Round-half-even to integer from positive f32 bits (value < 2^23).
__device__ __forceinline__ int rne_int_from_bits(uint32_t qbits) {
    int ef = (int)((qbits >> 23) & 0xFFu);
    if (ef == 0) return 0;
    uint32_t M = (qbits & 0x7FFFFFu) | 0x800000u;
    int sh = 150 - ef;
    if (sh <= 0) return (int)(M << (-sh));
    if (sh >= 25) return 0;
    uint32_t base = M >> sh;
    uint32_t r    = M & ((1u << sh) - 1u);
    uint32_t half = 1u << (sh - 1);
    if (r > half || (r == half && (base & 1u))) base++;
    return (int)base;
}

// f32 -> fp16 RNE, result as widened-f32 bits (normal fp16 range only).
__device__ __forceinline__ uint32_t fp16_round_bits(uint32_t u) {
    uint32_t lsb = (u >> 13) & 1u;
    u += 0x0FFFu + lsb;
    u &= 0xFFFFE000u;
    return u;
}

// ---------- kernel ----------
// One block (256 threads) per row; each thread owns 4 float4 in registers;
// input read exactly once, outputs written exactly once.
__global__ __launch_bounds__(256) void Quantizer_38053410243327_kernel(
    const float* __restrict__ x,
    float* __restrict__ qout,      // rows*4096
    float* __restrict__ scales,    // rows
    float* __restrict__ outlier)   // rows*64
{
    const int row = blockIdx.x;
    const int t   = threadIdx.x;

    const float* __restrict__ xrow   = x + (size_t)row * ROWLEN;
    const float4* __restrict__ core4 = (const float4*)(xrow + RANK);

    // Outlier passthrough: 64 floats = 16 float4, threads 0..15.
    if (t < 16) {
        ((float4*)(outlier + (size_t)row * RANK))[t] = ((const float4*)xrow)[t];
    }

    // Load core into registers, tracking per-thread absmax.
    float4 v[4];
    float m = 0.0f;
#pragma unroll
    for (int k = 0; k < 4; ++k) {
        v[k] = core4[t + 256 * k];
        m = fmaxf(m, fmaxf(fmaxf(fabsf(v[k].x), fabsf(v[k].y)),
                           fmaxf(fabsf(v[k].z), fabsf(v[k].w))));
    }

    // Wave (64-lane) butterfly max, then cross-wave max via LDS.
#pragma unroll
    for (int off = 32; off > 0; off >>= 1)
        m = fmaxf(m, __shfl_xor(m, off));

    __shared__ float smax[4];
    if ((t & 63) == 0) smax[t >> 6] = m;
    __syncthreads();
    m = fmaxf(fmaxf(smax[0], smax[1]), fmaxf(smax[2], smax[3]));

    // XLA constant-divisor rewrite: scale_pre = m * RN32(1/7).
    // v_mul_f32 is exact-RNE under any flags (single op, nothing to fuse).
    const float pre = m * __uint_as_float(0x3E124925u);   // RN32(1/7)
    const uint32_t sbits = fp16_round_bits(__float_as_uint(pre));
    const float s = __uint_as_float(sbits);
    if (t == 0) scales[row] = s;

    const float rs = 1.0f / s;   // fast-path approximation only

    float4* __restrict__ qrow = (float4*)(qout + (size_t)row * HIDDEN);
#pragma unroll
    for (int k = 0; k < 4; ++k) {
        float elems[4] = { v[k].x, v[k].y, v[k].z, v[k].w };
        float res[4];
#pragma unroll
        for (int j = 0; j < 4; ++j) {
            const uint32_t vb = __float_as_uint(elems[j]);
            const uint32_t ub = vb & 0x7FFFFFFFu;
            const float u  = __uint_as_float(ub);
            const float tq = u * rs;              // |err| <= ~3e-6 abs
            const float fr = tq - floorf(tq);
            int ki;
            if (fabsf(fr - 0.5f) < 5e-5f && tq < 7.45f) {
                // Exact: RN32 quotient (IEEE division), then half-even int.
                ki = rne_int_from_bits(softdiv_rn32_bits(ub, sbits));
            } else {
                ki = (int)rintf(tq);              // all rules agree off-boundary
            }
            if (ki > 7) ki = 7;                   // clip
            res[j] = __uint_as_float(__float_as_uint((float)ki) | (vb & 0x80000000u));
        }
        float4 q4 = { res[0], res[1], res[2], res[3] };
        qrow[t + 256 * k] = q4;
    }
}

extern "C" void kernel_launch(void* const* d_in, const int* in_sizes, int n_in,
                              void* d_out, int out_size, void* d_ws, size_t ws_size,
                              hipStream_t stream) {
    const float* x = (const float*)d_in[0];
    const int rows = in_sizes[0] / ROWLEN;   // 16384

    float* out     = (float*)d_out;
    float* qout    = out;                         // rows*4096
    float* scales  = out + (size_t)rows * HIDDEN; // rows
    float* outlier = scales + rows;               // rows*64

    Quantizer_38053410243327_kernel<<<rows, 256, 0, stream>>>(x, qout, scales, outlier);
}

// Round 11
// 93.146 us; speedup vs baseline: 1.0855x; 1.0855x over previous
//
#include <hip/hip_runtime.h>
#include <stdint.h>

#define HIDDEN 4096
#define RANK 64
#define ROWLEN (HIDDEN + RANK)   // 4160

// ============================================================================
// CORRECTNESS (do not touch — R10 passed, absmax 0.0):
//   golden = XLA-CPU compiled arithmetic, NOT literal numpy:
//     scale = f16_RNE( RN32( m * RN32(1/7) ) )   [const-div rewritten to mul]
//     q     = clip( rne( RN32( core / scale ) ), +-7 )  [data-dep div stays true]
//   Implemented with integer-exact softdiv on guard-band lanes; v_mul_f32 /
//   v_rndne_f32 are exact-RNE under any compiler flags.
// R11: nontemporal loads/stores (streaming, zero reuse) to close the
//   5.40 -> 6.3 TB/s gap. Arithmetic unchanged.
// ============================================================================

typedef __attribute__((ext_vector_type(4))) float f32x4;

// IEEE RN32 division a/b for positive normal a,b via integer math (immune to
// compiler FP modes). Audited: 1.0/7.0 -> 0x3E124925.
__device__ __forceinline__ uint32_t softdiv_rn32_bits(uint32_t abits, uint32_t bbits) {
    uint32_t Ma = (abits & 0x7FFFFFu) | 0x800000u;
    uint32_t Mb = (bbits & 0x7FFFFFu) | 0x800000u;
    int Ea = (int)((abits >> 23) & 0xFFu);
    int Eb = (int)((bbits >> 23) & 0xFFu);
    uint64_t num = ((uint64_t)Ma) << 25;
    uint64_t qi  = num / (uint64_t)Mb;
    uint64_t rem = num - qi * (uint64_t)Mb;
    int sh = (uint32_t)(qi >> 25) ? 2 : 1;
    uint32_t M  = (uint32_t)(qi >> sh);
    uint32_t rb = ((uint32_t)(qi >> (sh - 1))) & 1u;
    uint32_t st = ((((uint32_t)qi) & (uint32_t)(sh - 1)) != 0u) | (rem != 0ull);
    if (rb && (st || (M & 1u))) M++;
    int E = sh + Ea - Eb - 25;
    if (M == (1u << 24)) { M >>= 1; E += 1; }
    return ((uint32_t)(E + 150) << 23) | (M & 0x7FFFFFu);
}

// Round-half-even to integer from positive f32 bits (value < 2^23).
__device__ __forceinline__ int rne_int_from_bits(uint32_t qbits) {
    int ef = (int)((qbits >> 23) & 0xFFu);
    if (ef == 0) return 0;
    uint32_t M = (qbits & 0x7FFFFFu) | 0x800000u;
    int sh = 150 - ef;
    if (sh <= 0) return (int)(M << (-sh));
    if (sh >= 25) return 0;
    uint32_t base = M >> sh;
    uint32_t r    = M & ((1u << sh) - 1u);
    uint32_t half = 1u << (sh - 1);
    if (r > half || (r == half && (base & 1u))) base++;
    return (int)base;
}

// f32 -> fp16 RNE, result as widened-f32 bits (normal fp16 range only).
__device__ __forceinline__ uint32_t fp16_round_bits(uint32_t u) {
    uint32_t lsb = (u >> 13) & 1u;
    u += 0x0FFFu + lsb;
    u &= 0xFFFFE000u;
    return u;
}

// ---------- kernel ----------
// One block (256 threads) per row; each thread owns 4 f32x4 in registers;
// input read exactly once (nontemporal), outputs written once (nontemporal).
__global__ __launch_bounds__(256) void Quantizer_38053410243327_kernel(
    const float* __restrict__ x,
    float* __restrict__ qout,      // rows*4096
    float* __restrict__ scales,    // rows
    float* __restrict__ outlier)   // rows*64
{
    const int row = blockIdx.x;
    const int t   = threadIdx.x;

    const float* __restrict__ xrow   = x + (size_t)row * ROWLEN;
    const f32x4* __restrict__ core4  = (const f32x4*)(xrow + RANK);

    // Outlier passthrough: 64 floats = 16 f32x4, threads 0..15.
    if (t < 16) {
        f32x4 o = __builtin_nontemporal_load(&((const f32x4*)xrow)[t]);
        __builtin_nontemporal_store(o, &((f32x4*)(outlier + (size_t)row * RANK))[t]);
    }

    // Load core into registers (streaming), tracking per-thread absmax.
    f32x4 v[4];
    float m = 0.0f;
#pragma unroll
    for (int k = 0; k < 4; ++k) {
        v[k] = __builtin_nontemporal_load(&core4[t + 256 * k]);
        m = fmaxf(m, fmaxf(fmaxf(fabsf(v[k].x), fabsf(v[k].y)),
                           fmaxf(fabsf(v[k].z), fabsf(v[k].w))));
    }

    // Wave (64-lane) butterfly max, then cross-wave max via LDS.
#pragma unroll
    for (int off = 32; off > 0; off >>= 1)
        m = fmaxf(m, __shfl_xor(m, off));

    __shared__ float smax[4];
    if ((t & 63) == 0) smax[t >> 6] = m;
    __syncthreads();
    m = fmaxf(fmaxf(smax[0], smax[1]), fmaxf(smax[2], smax[3]));

    // XLA constant-divisor rewrite: scale_pre = m * RN32(1/7) (exact v_mul).
    const float pre = m * __uint_as_float(0x3E124925u);
    const uint32_t sbits = fp16_round_bits(__float_as_uint(pre));
    const float s = __uint_as_float(sbits);
    if (t == 0) scales[row] = s;

    const float rs = 1.0f / s;   // fast-path approximation only

    f32x4* __restrict__ qrow = (f32x4*)(qout + (size_t)row * HIDDEN);
#pragma unroll
    for (int k = 0; k < 4; ++k) {
        float elems[4] = { v[k].x, v[k].y, v[k].z, v[k].w };
        float res[4];
#pragma unroll
        for (int j = 0; j < 4; ++j) {
            const uint32_t vb = __float_as_uint(elems[j]);
            const uint32_t ub = vb & 0x7FFFFFFFu;
            const float u  = __uint_as_float(ub);
            const float tq = u * rs;              // |err| <= ~3e-6 abs
            const float fr = tq - floorf(tq);
            int ki;
            if (fabsf(fr - 0.5f) < 5e-5f && tq < 7.45f) {
                // Exact: RN32 quotient (IEEE division), then half-even int.
                ki = rne_int_from_bits(softdiv_rn32_bits(ub, sbits));
            } else {
                ki = (int)rintf(tq);              // all rules agree off-boundary
            }
            if (ki > 7) ki = 7;                   // clip
            res[j] = __uint_as_float(__float_as_uint((float)ki) | (vb & 0x80000000u));
        }
        f32x4 q4 = { res[0], res[1], res[2], res[3] };
        __builtin_nontemporal_store(q4, &qrow[t + 256 * k]);
    }
}

extern "C" void kernel_launch(void* const* d_in, const int* in_sizes, int n_in,
                              void* d_out, int out_size, void* d_ws, size_t ws_size,
                              hipStream_t stream) {
    const float* x = (const float*)d_in[0];
    const int rows = in_sizes[0] / ROWLEN;   // 16384

    float* out     = (float*)d_out;
    float* qout    = out;                         // rows*4096
    float* scales  = out + (size_t)rows * HIDDEN; // rows
    float* outlier = scales + rows;               // rows*64

    Quantizer_38053410243327_kernel<<<rows, 256, 0, stream>>>(x, qout, scales, outlier);
}